// Round 8
// baseline (616.738 us; speedup 1.0000x reference)
//
#include <hip/hip_runtime.h>

typedef unsigned short u16;
typedef __attribute__((ext_vector_type(8))) short short8;
typedef __attribute__((ext_vector_type(4))) unsigned short u16x4;
typedef __attribute__((ext_vector_type(4))) float f32x4;

#define DEV __device__ __forceinline__
#define VMW(n) asm volatile("s_waitcnt vmcnt(" #n ")" ::: "memory")

DEV float bf2f(u16 u) { return __uint_as_float(((unsigned int)u) << 16); }
DEV u16 f2bf(float f) {
  unsigned int u = __float_as_uint(f);
  u += 0x7FFF + ((u >> 16) & 1);
  return (u16)(u >> 16);
}

DEV float redmax16(float v) {
  v = fmaxf(v, __shfl_xor(v, 1));
  v = fmaxf(v, __shfl_xor(v, 2));
  v = fmaxf(v, __shfl_xor(v, 4));
  v = fmaxf(v, __shfl_xor(v, 8));
  return v;
}
DEV float redsum16(float v) {
  v += __shfl_xor(v, 1);
  v += __shfl_xor(v, 2);
  v += __shfl_xor(v, 4);
  v += __shfl_xor(v, 8);
  return v;
}

// ---------------- transpose + cast f32 -> bf16, 32x32 tiles ----------------
__global__ __launch_bounds__(256) void transpose_f32_bf16(const float* __restrict__ in,
                                                          u16* __restrict__ out,
                                                          int R, int C) {
  __shared__ u16 tile[32][33];
  int tx = threadIdx.x & 31, ty = threadIdx.x >> 5;  // 32 x 8
  int r0 = blockIdx.y * 32, c0 = blockIdx.x * 32;
#pragma unroll
  for (int i = 0; i < 32; i += 8)
    tile[ty + i][tx] = f2bf(in[(size_t)(r0 + ty + i) * C + c0 + tx]);
  __syncthreads();
#pragma unroll
  for (int i = 0; i < 32; i += 8)
    out[(size_t)(c0 + ty + i) * R + r0 + tx] = tile[tx][ty + i];
}

// ---------------- transpose V third of qkv -> vT[b,h][64][4096] -------------
__global__ __launch_bounds__(256) void transpose_v(const u16* __restrict__ qkv,
                                                   u16* __restrict__ vT) {
  __shared__ u16 tile[32][33];
  int tx = threadIdx.x & 31, ty = threadIdx.x >> 5;  // 32 x 8
  int s0 = blockIdx.x * 32, d0 = blockIdx.y * 32;
  int bh = blockIdx.z;
  const u16* src = qkv + (size_t)(bh >> 4) * 4096 * 3072 + 2048 + (bh & 15) * 64;
#pragma unroll
  for (int i = 0; i < 32; i += 8)
    tile[ty + i][tx] = src[(size_t)(s0 + ty + i) * 3072 + d0 + tx];
  __syncthreads();
  u16* dst = vT + (size_t)bh * 64 * 4096;
#pragma unroll
  for (int i = 0; i < 32; i += 8)
    dst[(size_t)(d0 + ty + i) * 4096 + s0 + tx] = tile[tx][ty + i];
}

// ---------------- RMSNorm: 8192 rows x 1024, f32 in -> bf16 out ----------------
__global__ __launch_bounds__(256) void rmsnorm_kernel(const float* __restrict__ x,
                                                      const float* __restrict__ w,
                                                      u16* __restrict__ xn) {
  int row = blockIdx.x, t = threadIdx.x;
  const float4* xr = reinterpret_cast<const float4*>(x + (size_t)row * 1024);
  float4 v = xr[t];
  float ss = v.x * v.x + v.y * v.y + v.z * v.z + v.w * v.w;
#pragma unroll
  for (int d = 1; d < 64; d <<= 1) ss += __shfl_xor(ss, d);
  __shared__ float red[4];
  if ((t & 63) == 0) red[t >> 6] = ss;
  __syncthreads();
  float tot = red[0] + red[1] + red[2] + red[3];
  float inv = rsqrtf(tot * (1.0f / 1024.0f) + 1e-6f);
  float4 wv = reinterpret_cast<const float4*>(w)[t];
  u16x4 o;
  o[0] = f2bf(v.x * inv * wv.x);
  o[1] = f2bf(v.y * inv * wv.y);
  o[2] = f2bf(v.z * inv * wv.z);
  o[3] = f2bf(v.w * inv * wv.w);
  *reinterpret_cast<u16x4*>(xn + (size_t)row * 1024 + t * 4) = o;
}

// ------- RoPE in-place on q,k halves of qkv (bf16); q additionally *0.125 ----
__global__ __launch_bounds__(256) void rope_kernel(u16* __restrict__ qkv,
                                                   const float* __restrict__ sp,
                                                   const float* __restrict__ cp) {
  size_t i = (size_t)blockIdx.x * 256 + threadIdx.x;  // pair index, 8192*1024 total
  int row = (int)(i >> 10);
  int e2 = (int)(i & 1023);
  int pos = row & 4095;
  int elem = e2 * 2;  // within [q(1024) | k(1024)]
  int d = elem & 63;
  size_t off = (size_t)row * 3072 + elem;
  float sc = (elem < 1024) ? 0.125f : 1.0f;  // fold 1/sqrt(64) into q (exact)
  float xe = bf2f(qkv[off]), xo = bf2f(qkv[off + 1]);
  float s0 = sp[pos * 64 + d], s1 = sp[pos * 64 + d + 1];
  float c0 = cp[pos * 64 + d], c1 = cp[pos * 64 + d + 1];
  qkv[off] = f2bf((xe * c0 - xo * s0) * sc);
  qkv[off + 1] = f2bf((xo * c1 + xe * s1) * sc);
}

// ============== 8-phase pipelined GEMM: C = A[M][K] @ BT[N][K]^T + bias =====
// BN=256 fixed, BK=64, 8 waves (2M x 4N). MI=8 -> BM=256, dbuf, 4 phases/tile.
// MI=4 -> BM=128, triple-buf, 2 phases/tile. K-slice staging (2 kslots/slice),
// counted vmcnt(6) never drained in steady state, barriers only where data
// collectivity is needed, setprio around MFMA clusters, conflict-free
// kslot-major LDS ([kslot][row][16B]). L2-pinning XCD block mapping.
// MODE 0: bf16 out; 1: bf16+GELU; 2: f32 out. PINX: pin bx per XCD (else by).
template <int MI, int MODE, int PINX>
__global__ __launch_bounds__(512) void gemm8p(const u16* __restrict__ A,
                                              const u16* __restrict__ BT,
                                              const float* __restrict__ bias,
                                              void* __restrict__ Cout,
                                              int K, int ldc, int NBX, int NBY) {
  constexpr int BM = MI * 32;
  constexpr int ABYTES = BM * 128;           // 8 kslots x BM rows x 16B
  constexpr int BUFB = ABYTES + 32768;       // + 8 kslots x 256 rows x 16B
  constexpr int NBUF = (MI == 8) ? 2 : 3;
  __shared__ float4 lds_v[NBUF * BUFB / 16];
  char* lds = (char*)lds_v;

  int t = threadIdx.x;
  int w = t >> 6, l = t & 63, c = l & 15, g = l >> 4;
  int wm = w >> 2, wn = w & 3;

  // ---- L2-pinning block mapping (assumes XCD ~ bid%8; perf-only) ----
  int bid = blockIdx.x;
  int x8 = bid & 7, k8 = bid >> 3;
  int bx, by;
  if (PINX) {  // pin B-panel per XCD (OUT: NBX=4)
    bx = x8 % NBX;
    by = k8 + (x8 / NBX) * ((NBX * NBY) >> 3);
  } else {  // pin A-panels per XCD (QKV/FF)
    int nyg = NBY >> 3;
    by = x8 * nyg + k8 / NBX;
    bx = k8 % NBX;
  }

  size_t m0 = (size_t)by * BM, n0 = (size_t)bx * 256;
  const u16* Ab = A + m0 * K;
  const u16* Bb = BT + n0 * K;
  int KT = K >> 6;

  f32x4 zero4 = {0.f, 0.f, 0.f, 0.f};
  f32x4 acc[MI][4];
#pragma unroll
  for (int a = 0; a < MI; ++a)
#pragma unroll
    for (int b2 = 0; b2 < 4; ++b2) acc[a][b2] = zero4;

  // stage one k-slice of a tile. MI==8: slice s in [0,4), 2 kslots, 2 loads.
  // MI==4: slice s in [0,2), 4 kslots, 3 loads. Dest linear (wave-uniform+l*16).
  auto stage_slice = [&](int tile, int s) {
    char* dst = lds + (tile % NBUF) * BUFB;
    int kt = tile << 6;
    if constexpr (MI == 8) {
      int ua = 512 * s + t;  // kslot = ua>>8, row = ua&255
      const u16* srcA = Ab + (size_t)(ua & 255) * K + kt + (ua >> 8) * 8;
      __builtin_amdgcn_global_load_lds(
          (const __attribute__((address_space(1))) unsigned int*)srcA,
          (__attribute__((address_space(3))) unsigned int*)(dst + ua * 16), 16, 0, 0);
      int ub = 512 * s + t;
      const u16* srcB = Bb + (size_t)(ub & 255) * K + kt + (ub >> 8) * 8;
      __builtin_amdgcn_global_load_lds(
          (const __attribute__((address_space(1))) unsigned int*)srcB,
          (__attribute__((address_space(3))) unsigned int*)(dst + ABYTES + ub * 16), 16, 0, 0);
    } else {
      int ua = 512 * s + t;  // kslot = ua>>7, row = ua&127
      const u16* srcA = Ab + (size_t)(ua & 127) * K + kt + (ua >> 7) * 8;
      __builtin_amdgcn_global_load_lds(
          (const __attribute__((address_space(1))) unsigned int*)srcA,
          (__attribute__((address_space(3))) unsigned int*)(dst + ua * 16), 16, 0, 0);
#pragma unroll
      for (int j = 0; j < 2; ++j) {
        int ub = 1024 * s + j * 512 + t;
        const u16* srcB = Bb + (size_t)(ub & 255) * K + kt + (ub >> 8) * 8;
        __builtin_amdgcn_global_load_lds(
            (const __attribute__((address_space(1))) unsigned int*)srcB,
            (__attribute__((address_space(3))) unsigned int*)(dst + ABYTES + ub * 16), 16, 0, 0);
      }
    }
  };

  // one phase: 16 MFMA on quadrant (kk, mih) of the wave tile
  auto compute_phase = [&](const char* buf, int kk, int mih) {
    const char* Bbase = buf + ABYTES;
    short8 av[4], bv[4];
#pragma unroll
    for (int nj = 0; nj < 4; ++nj) {
      int row = wn * 64 + 16 * nj + c;
      bv[nj] = *reinterpret_cast<const short8*>(Bbase + (((4 * kk + g) * 256 + row) << 4));
    }
#pragma unroll
    for (int i = 0; i < 4; ++i) {
      int row = wm * (MI * 16) + 16 * (mih * 4 + i) + c;
      av[i] = *reinterpret_cast<const short8*>(buf + (((4 * kk + g) * BM + row) << 4));
    }
    __builtin_amdgcn_s_setprio(1);
#pragma unroll
    for (int i = 0; i < 4; ++i)
#pragma unroll
      for (int nj = 0; nj < 4; ++nj)
        acc[mih * 4 + i][nj] =
            __builtin_amdgcn_mfma_f32_16x16x32_bf16(av[i], bv[nj], acc[mih * 4 + i][nj], 0, 0, 0);
    __builtin_amdgcn_s_setprio(0);
  };

  if constexpr (MI == 8) {
    // prologue: all 4 slices of tile 0 (8 loads/thread)
#pragma unroll
    for (int s = 0; s < 4; ++s) stage_slice(0, s);
    for (int tt = 0; tt < KT; ++tt) {
      const char* buf = lds + (tt & 1) * BUFB;
      bool a = (tt + 1 < KT);
      // phase 0 (kk=0, mi 0-3): issue next s0; wait slices 0,1 of tt
      if (a) stage_slice(tt + 1, 0);
      if (a) VMW(6); else VMW(4);
      __builtin_amdgcn_s_barrier();
      compute_phase(buf, 0, 0);
      // phase 1 (kk=0, mi 4-7)
      if (a) stage_slice(tt + 1, 1);
      compute_phase(buf, 0, 1);
      // phase 2 (kk=1, mi 0-3): issue next s2; wait slices 2,3 of tt
      if (a) stage_slice(tt + 1, 2);
      if (a) VMW(6); else VMW(0);
      __builtin_amdgcn_s_barrier();
      compute_phase(buf, 1, 0);
      // phase 3 (kk=1, mi 4-7)
      if (a) stage_slice(tt + 1, 3);
      compute_phase(buf, 1, 1);
    }
  } else {
    // prologue: tiles 0 and 1 (6 loads/thread each)
#pragma unroll
    for (int s = 0; s < 2; ++s) stage_slice(0, s);
#pragma unroll
    for (int s = 0; s < 2; ++s) stage_slice(1, s);
    for (int tt = 0; tt < KT; ++tt) {
      const char* buf = lds + (tt % 3) * BUFB;
      bool b2 = (tt + 2 < KT);
      // phase 0 (kk=0): wait tile tt landed (tt+1's 6 loads may fly)
      if (tt + 1 < KT) VMW(6); else VMW(0);
      __builtin_amdgcn_s_barrier();
      if (b2) stage_slice(tt + 2, 0);  // after barrier: no race with tt readers
      compute_phase(buf, 0, 0);
      // phase 1 (kk=1)
      if (b2) stage_slice(tt + 2, 1);
      compute_phase(buf, 1, 0);
    }
  }

  // ---- epilogue ----
#pragma unroll
  for (int nj = 0; nj < 4; ++nj) {
    int col = (int)n0 + wn * 64 + 16 * nj + c;
    float bvv = bias[col];
#pragma unroll
    for (int mi = 0; mi < MI; ++mi) {
      size_t rbase = m0 + wm * (MI * 16) + 16 * mi + 4 * g;
#pragma unroll
      for (int r = 0; r < 4; ++r) {
        float f = acc[mi][nj][r] + bvv;
        if (MODE == 1) f = 0.5f * f * (1.0f + erff(f * 0.70710678f));
        size_t oidx = (rbase + r) * (size_t)ldc + col;
        if (MODE == 2)
          ((float*)Cout)[oidx] = f;
        else
          ((u16*)Cout)[oidx] = f2bf(f);
      }
    }
  }
}

// ---------------- sliding-window causal attention ----------------
// 1 wave per 32-query tile, no barriers. grid = B*NH*(S/32) = 4096, block = 64.
// Q pre-scaled by 0.125. K frags direct global; V frags direct from vT.
__global__ __launch_bounds__(64, 4) void attn_kernel(const u16* __restrict__ qkv,
                                                     const u16* __restrict__ vT,
                                                     u16* __restrict__ comb) {
  int bid = blockIdx.x;
  int swz = ((bid & 7) << 9) + (bid >> 3);  // 4096/8 = 512 per XCD
  int qt = swz & 127, h = (swz >> 7) & 15, b = swz >> 11;
  int l = threadIdx.x, c = l & 15, g = l >> 4;
  int q0 = qt * 32;
  const u16* qb = qkv + (size_t)b * 4096 * 3072 + h * 64;
  const u16* kb = qb + 1024;
  const u16* vt = vT + (size_t)(b * 16 + h) * 64 * 4096;
  __shared__ u16 Pl[32 * 72];

  short8 qf[2][2];
#pragma unroll
  for (int mi = 0; mi < 2; ++mi)
#pragma unroll
    for (int kk = 0; kk < 2; ++kk)
      qf[mi][kk] = *reinterpret_cast<const short8*>(
          qb + (size_t)(q0 + 16 * mi + c) * 3072 + 32 * kk + 8 * g);

  f32x4 zero4 = {0.f, 0.f, 0.f, 0.f};
  f32x4 o[2][4];
  float mr[2][4], lr[2][4];
#pragma unroll
  for (int a = 0; a < 2; ++a)
#pragma unroll
    for (int d2 = 0; d2 < 4; ++d2) {
      o[a][d2] = zero4;
      mr[a][d2] = -1e30f;
      lr[a][d2] = 0.f;
    }

  int t_lo = (q0 >= 480) ? ((q0 - 480) >> 6) : 0;
  int t_hi = (q0 + 31) >> 6;
  for (int tt = t_lo; tt <= t_hi; ++tt) {
    int kt0 = tt * 64;
    f32x4 s[2][4];
#pragma unroll
    for (int a = 0; a < 2; ++a)
#pragma unroll
      for (int d2 = 0; d2 < 4; ++d2) s[a][d2] = zero4;

#pragma unroll
    for (int kk = 0; kk < 2; ++kk) {
      short8 kf[4];
#pragma unroll
      for (int nj = 0; nj < 4; ++nj)
        kf[nj] = *reinterpret_cast<const short8*>(
            kb + (size_t)(kt0 + 16 * nj + c) * 3072 + 32 * kk + 8 * g);
#pragma unroll
      for (int mi = 0; mi < 2; ++mi)
#pragma unroll
        for (int nj = 0; nj < 4; ++nj)
          s[mi][nj] = __builtin_amdgcn_mfma_f32_16x16x32_bf16(qf[mi][kk], kf[nj], s[mi][nj], 0, 0, 0);
    }

    // mask only on the boundary tiles (wave-uniform branch)
    bool mc = (tt == t_hi), mw = (tt == t_lo);
    if (mc | mw) {
#pragma unroll
      for (int mi = 0; mi < 2; ++mi)
#pragma unroll
        for (int nj = 0; nj < 4; ++nj)
#pragma unroll
          for (int r = 0; r < 4; ++r) {
            int qg = q0 + 16 * mi + 4 * g + r;
            int kg = kt0 + 16 * nj + c;
            if ((mc && kg > qg) || (mw && qg - kg >= 512)) s[mi][nj][r] = -1e30f;
          }
    }

#pragma unroll
    for (int mi = 0; mi < 2; ++mi)
#pragma unroll
      for (int r = 0; r < 4; ++r) {
        float tm = fmaxf(fmaxf(s[mi][0][r], s[mi][1][r]), fmaxf(s[mi][2][r], s[mi][3][r]));
        tm = redmax16(tm);
        float mn = fmaxf(mr[mi][r], tm);
        float a = __expf(mr[mi][r] - mn);
        mr[mi][r] = mn;
        float rs = 0.f;
        u16* pp = &Pl[(16 * mi + 4 * g + r) * 72 + c];
#pragma unroll
        for (int nj = 0; nj < 4; ++nj) {
          float p = __expf(s[mi][nj][r] - mn);
          rs += p;
          pp[16 * nj] = f2bf(p);  // natural k order, imm-offset ds_write_b16
        }
        rs = redsum16(rs);
        lr[mi][r] = lr[mi][r] * a + rs;
#pragma unroll
        for (int dj = 0; dj < 4; ++dj) o[mi][dj][r] *= a;
      }

    // PV: A-frag from Pl (natural order), B-frag = k-contiguous rows of vT
#pragma unroll
    for (int kk = 0; kk < 2; ++kk) {
      short8 pa[2];
#pragma unroll
      for (int mi = 0; mi < 2; ++mi)
        pa[mi] = *reinterpret_cast<const short8*>(&Pl[(16 * mi + c) * 72 + 32 * kk + 8 * g]);
      short8 bv[4];
#pragma unroll
      for (int dj = 0; dj < 4; ++dj)
        bv[dj] = *reinterpret_cast<const short8*>(
            vt + (size_t)(16 * dj + c) * 4096 + kt0 + 32 * kk + 8 * g);
#pragma unroll
      for (int mi = 0; mi < 2; ++mi)
#pragma unroll
        for (int dj = 0; dj < 4; ++dj)
          o[mi][dj] = __builtin_amdgcn_mfma_f32_16x16x32_bf16(pa[mi], bv[dj], o[mi][dj], 0, 0, 0);
    }
  }

  u16* ob = comb + (size_t)(b * 4096 + q0) * 5120 + h * 64;
#pragma unroll
  for (int mi = 0; mi < 2; ++mi)
#pragma unroll
    for (int r = 0; r < 4; ++r) {
      float inv = __builtin_amdgcn_rcpf(lr[mi][r]);
#pragma unroll
      for (int dj = 0; dj < 4; ++dj)
        ob[(size_t)(16 * mi + 4 * g + r) * 5120 + 16 * dj + c] = f2bf(o[mi][dj][r] * inv);
    }
}

// ---------------- launch ----------------
extern "C" void kernel_launch(void* const* d_in, const int* in_sizes, int n_in,
                              void* d_out, int out_size, void* d_ws, size_t ws_size,
                              hipStream_t stream) {
  const float* x = (const float*)d_in[0];
  const float* sinp = (const float*)d_in[1];
  const float* cosp = (const float*)d_in[2];
  const float* norm_w = (const float*)d_in[3];
  const float* w_qkv = (const float*)d_in[4];
  const float* b_qkv = (const float*)d_in[5];
  const float* w_in = (const float*)d_in[6];
  const float* b_in = (const float*)d_in[7];
  const float* w_out = (const float*)d_in[8];
  const float* b_out = (const float*)d_in[9];
  float* out = (float*)d_out;

  char* ws = (char*)d_ws;
  u16* xn = (u16*)(ws);                        // 8192*1024*2      = 16,777,216
  u16* vT = (u16*)(ws);                        // aliases xn (xn dead after FF gemm)
  u16* qkv = (u16*)(ws + 16777216);            // 8192*3072*2      = 50,331,648
  u16* comb = (u16*)(ws + 67108864);           // 8192*5120*2      = 83,886,080
  u16* wqkvT = (u16*)(ws + 150994944);         // 3072*1024*2      = 6,291,456
  u16* winT = (u16*)(ws + 157286400);          // 4096*1024*2      = 8,388,608
  u16* woutT = (u16*)(ws + 165675008);         // 1024*5120*2      = 10,485,760

  transpose_f32_bf16<<<dim3(3072 / 32, 1024 / 32), 256, 0, stream>>>(w_qkv, wqkvT, 1024, 3072);
  transpose_f32_bf16<<<dim3(4096 / 32, 1024 / 32), 256, 0, stream>>>(w_in, winT, 1024, 4096);
  transpose_f32_bf16<<<dim3(1024 / 32, 5120 / 32), 256, 0, stream>>>(w_out, woutT, 5120, 1024);

  rmsnorm_kernel<<<8192, 256, 0, stream>>>(x, norm_w, xn);

  // qkv = xn @ w_qkv + b_qkv   (bf16 out)  grid 12x32 = 384, pin A-panels
  gemm8p<8, 0, 0><<<384, 512, 0, stream>>>(xn, wqkvT, b_qkv, qkv, 1024, 3072, 12, 32);

  rope_kernel<<<32768, 256, 0, stream>>>(qkv, sinp, cosp);

  // ff = gelu(xn @ w_in + b_in) -> comb cols [1024,5120)  grid 16x32 = 512
  gemm8p<8, 1, 0><<<512, 512, 0, stream>>>(xn, winT, b_in, comb + 1024, 1024, 5120, 16, 32);

  // vT[b,h][d][s] = V  (into xn's region; xn dead after FF gemm)
  transpose_v<<<dim3(128, 2, 32), 256, 0, stream>>>(qkv, vT);

  attn_kernel<<<4096, 64, 0, stream>>>(qkv, vT, comb);

  // out = comb @ w_out + b_out  (f32 out)  grid 4x64 = 256, pin B-panel per XCD
  gemm8p<4, 2, 1><<<256, 512, 0, stream>>>(comb, woutT, b_out, out, 5120, 1024, 4, 64);
}

// Round 9
// 431.900 us; speedup vs baseline: 1.4280x; 1.4280x over previous
//
#include <hip/hip_runtime.h>

typedef unsigned short u16;
typedef __attribute__((ext_vector_type(8))) short short8;
typedef __attribute__((ext_vector_type(4))) unsigned short u16x4;
typedef __attribute__((ext_vector_type(4))) float f32x4;

#define DEV __device__ __forceinline__
#define VMW(n) asm volatile("s_waitcnt vmcnt(" #n ")" ::: "memory")

DEV float bf2f(u16 u) { return __uint_as_float(((unsigned int)u) << 16); }
DEV u16 f2bf(float f) {
  unsigned int u = __float_as_uint(f);
  u += 0x7FFF + ((u >> 16) & 1);
  return (u16)(u >> 16);
}

DEV float redmax16(float v) {
  v = fmaxf(v, __shfl_xor(v, 1));
  v = fmaxf(v, __shfl_xor(v, 2));
  v = fmaxf(v, __shfl_xor(v, 4));
  v = fmaxf(v, __shfl_xor(v, 8));
  return v;
}
DEV float redsum16(float v) {
  v += __shfl_xor(v, 1);
  v += __shfl_xor(v, 2);
  v += __shfl_xor(v, 4);
  v += __shfl_xor(v, 8);
  return v;
}

// ---------------- transpose + cast f32 -> bf16, 32x32 tiles ----------------
__global__ __launch_bounds__(256) void transpose_f32_bf16(const float* __restrict__ in,
                                                          u16* __restrict__ out,
                                                          int R, int C) {
  __shared__ u16 tile[32][33];
  int tx = threadIdx.x & 31, ty = threadIdx.x >> 5;  // 32 x 8
  int r0 = blockIdx.y * 32, c0 = blockIdx.x * 32;
#pragma unroll
  for (int i = 0; i < 32; i += 8)
    tile[ty + i][tx] = f2bf(in[(size_t)(r0 + ty + i) * C + c0 + tx]);
  __syncthreads();
#pragma unroll
  for (int i = 0; i < 32; i += 8)
    out[(size_t)(c0 + ty + i) * R + r0 + tx] = tile[tx][ty + i];
}

// ---------------- transpose V third of qkv -> vT[b,h][64][4096] -------------
__global__ __launch_bounds__(256) void transpose_v(const u16* __restrict__ qkv,
                                                   u16* __restrict__ vT) {
  __shared__ u16 tile[32][33];
  int tx = threadIdx.x & 31, ty = threadIdx.x >> 5;  // 32 x 8
  int s0 = blockIdx.x * 32, d0 = blockIdx.y * 32;
  int bh = blockIdx.z;
  const u16* src = qkv + (size_t)(bh >> 4) * 4096 * 3072 + 2048 + (bh & 15) * 64;
#pragma unroll
  for (int i = 0; i < 32; i += 8)
    tile[ty + i][tx] = src[(size_t)(s0 + ty + i) * 3072 + d0 + tx];
  __syncthreads();
  u16* dst = vT + (size_t)bh * 64 * 4096;
#pragma unroll
  for (int i = 0; i < 32; i += 8)
    dst[(size_t)(d0 + ty + i) * 4096 + s0 + tx] = tile[tx][ty + i];
}

// ---------------- RMSNorm: 8192 rows x 1024, f32 in -> bf16 out ----------------
__global__ __launch_bounds__(256) void rmsnorm_kernel(const float* __restrict__ x,
                                                      const float* __restrict__ w,
                                                      u16* __restrict__ xn) {
  int row = blockIdx.x, t = threadIdx.x;
  const float4* xr = reinterpret_cast<const float4*>(x + (size_t)row * 1024);
  float4 v = xr[t];
  float ss = v.x * v.x + v.y * v.y + v.z * v.z + v.w * v.w;
#pragma unroll
  for (int d = 1; d < 64; d <<= 1) ss += __shfl_xor(ss, d);
  __shared__ float red[4];
  if ((t & 63) == 0) red[t >> 6] = ss;
  __syncthreads();
  float tot = red[0] + red[1] + red[2] + red[3];
  float inv = rsqrtf(tot * (1.0f / 1024.0f) + 1e-6f);
  float4 wv = reinterpret_cast<const float4*>(w)[t];
  u16x4 o;
  o[0] = f2bf(v.x * inv * wv.x);
  o[1] = f2bf(v.y * inv * wv.y);
  o[2] = f2bf(v.z * inv * wv.z);
  o[3] = f2bf(v.w * inv * wv.w);
  *reinterpret_cast<u16x4*>(xn + (size_t)row * 1024 + t * 4) = o;
}

// ------- RoPE in-place, vectorized: one block per qkv row; q scaled 0.125 ----
// thread t handles 8 elems (4 pairs) at e0 = t*8 within [q(1024)|k(1024)].
__global__ __launch_bounds__(256) void rope_kernel(u16* __restrict__ qkv,
                                                   const float* __restrict__ sp,
                                                   const float* __restrict__ cp) {
  int row = blockIdx.x;  // 8192 rows
  int t = threadIdx.x;
  int pos = row & 4095;
  int e0 = t * 8;
  float sc = (e0 < 1024) ? 0.125f : 1.0f;  // fold 1/sqrt(64) into q (exact)
  int d0 = e0 & 63;
  u16* p = qkv + (size_t)row * 3072 + e0;
  short8 v = *reinterpret_cast<const short8*>(p);
  float4 s01 = *reinterpret_cast<const float4*>(sp + pos * 64 + d0);
  float4 s23 = *reinterpret_cast<const float4*>(sp + pos * 64 + d0 + 4);
  float4 c01 = *reinterpret_cast<const float4*>(cp + pos * 64 + d0);
  float4 c23 = *reinterpret_cast<const float4*>(cp + pos * 64 + d0 + 4);
  short8 o;
  float xe, xo;
  xe = bf2f((u16)v[0]); xo = bf2f((u16)v[1]);
  o[0] = (short)f2bf((xe * c01.x - xo * s01.x) * sc);
  o[1] = (short)f2bf((xo * c01.y + xe * s01.y) * sc);
  xe = bf2f((u16)v[2]); xo = bf2f((u16)v[3]);
  o[2] = (short)f2bf((xe * c01.z - xo * s01.z) * sc);
  o[3] = (short)f2bf((xo * c01.w + xe * s01.w) * sc);
  xe = bf2f((u16)v[4]); xo = bf2f((u16)v[5]);
  o[4] = (short)f2bf((xe * c23.x - xo * s23.x) * sc);
  o[5] = (short)f2bf((xo * c23.y + xe * s23.y) * sc);
  xe = bf2f((u16)v[6]); xo = bf2f((u16)v[7]);
  o[6] = (short)f2bf((xe * c23.z - xo * s23.z) * sc);
  o[7] = (short)f2bf((xo * c23.w + xe * s23.w) * sc);
  *reinterpret_cast<short8*>(p) = o;
}

// ============ Pipelined GEMM (bench-R5 exact): C = A @ BT^T + bias ==========
// BM=256, BN=128, BK=64; 8 waves (4M x 2N), per-wave 64x64.
// Triple-buffered LDS (144 KB), staging 1 tile ahead, counted vmcnt(6) at
// tile boundary (never 0 in steady loop), setprio around MFMA, raw s_barrier.
// XOR-swizzled row-major LDS (bank-optimal for b128), coalesced staging
// (8 lanes per 128B row segment). mode 0: bf16; 1: bf16+GELU; 2: f32.

DEV void stage_half(const u16* __restrict__ gbase, int K, int kt, char* dst, int w, int l) {
  // 128 rows x 64k (16 KB). wave w covers segments s=2w,2w+1 (1 KB each, linear dest).
  // dest byte s*1024+16*l -> row = s*8 + (l>>3), dslot = l&7.
  // source k-slot pre-swizzled: ksrc = dslot ^ (row&7) = (l&7) ^ (l>>3).
#pragma unroll
  for (int j = 0; j < 2; ++j) {
    int s = w * 2 + j;
    int row = s * 8 + (l >> 3);
    int ksrc = ((l & 7) ^ (l >> 3)) << 3;
    const u16* src = gbase + (size_t)row * K + kt + ksrc;
    __builtin_amdgcn_global_load_lds(
        (const __attribute__((address_space(1))) unsigned int*)src,
        (__attribute__((address_space(3))) unsigned int*)(dst + s * 1024 + l * 16),
        16, 0, 0);
  }
}

DEV short8 ldfrag(const char* base, int row, int slot) {
  // swizzled read: byte = row*128 + ((slot ^ (row&7))<<4)
  return *reinterpret_cast<const short8*>(base + row * 128 + (((slot ^ (row & 7)) << 4)));
}

__global__ __launch_bounds__(512) void gemm256(const u16* __restrict__ A,
                                               const u16* __restrict__ BT,
                                               const float* __restrict__ bias,
                                               void* __restrict__ Cout,
                                               int K, int ldc, int mode) {
  __shared__ float4 lds_v[9216];  // 147456 B = 3 bufs x (A 32KB + B 16KB)
  char* lds = (char*)lds_v;
  int t = threadIdx.x;
  int w = t >> 6, l = t & 63, c = l & 15, g = l >> 4;
  int wr = w >> 1, wc = w & 1;
  size_t m0 = (size_t)blockIdx.y * 256, n0 = (size_t)blockIdx.x * 128;
  const u16* Ab = A + m0 * K;
  const u16* Bb = BT + n0 * K;
  int KT = K >> 6;

  f32x4 zero4 = {0.f, 0.f, 0.f, 0.f};
  f32x4 acc[4][4];
#pragma unroll
  for (int a = 0; a < 4; ++a)
#pragma unroll
    for (int b2 = 0; b2 < 4; ++b2) acc[a][b2] = zero4;

  // prologue: stage tiles 0 and 1 (6 loads/thread each)
#pragma unroll
  for (int pt = 0; pt < 2; ++pt) {
    int boff = pt * 49152;
    stage_half(Ab, K, pt * 64, lds + boff, w, l);
    stage_half(Ab + (size_t)128 * K, K, pt * 64, lds + boff + 16384, w, l);
    stage_half(Bb, K, pt * 64, lds + boff + 32768, w, l);
  }
  VMW(6);  // tile 0 landed
  __builtin_amdgcn_s_barrier();

  for (int tt = 0; tt < KT; ++tt) {
    const char* Abuf = lds + (tt % 3) * 49152;
    const char* Bbuf = Abuf + 32768;
    int b2off = ((tt + 2) % 3) * 49152;
    int kt2 = (tt + 2) * 64;
    bool pf = (tt + 2 < KT);

    // ---- phase 0 (k 0..31): prefetch A halves of t+2, compute ----
    if (pf) {
      stage_half(Ab, K, kt2, lds + b2off, w, l);
      stage_half(Ab + (size_t)128 * K, K, kt2, lds + b2off + 16384, w, l);
    }
    {
      short8 bv[4], av[4];
#pragma unroll
      for (int nj = 0; nj < 4; ++nj) bv[nj] = ldfrag(Bbuf, wc * 64 + 16 * nj + c, g);
#pragma unroll
      for (int mi = 0; mi < 4; ++mi) av[mi] = ldfrag(Abuf, wr * 64 + 16 * mi + c, g);
      __builtin_amdgcn_s_setprio(1);
#pragma unroll
      for (int mi = 0; mi < 4; ++mi)
#pragma unroll
        for (int nj = 0; nj < 4; ++nj)
          acc[mi][nj] = __builtin_amdgcn_mfma_f32_16x16x32_bf16(av[mi], bv[nj], acc[mi][nj], 0, 0, 0);
      __builtin_amdgcn_s_setprio(0);
    }
    __builtin_amdgcn_s_barrier();

    // ---- phase 1 (k 32..63): prefetch B half of t+2, compute ----
    if (pf) stage_half(Bb, K, kt2, lds + b2off + 32768, w, l);
    {
      short8 bv[4], av[4];
#pragma unroll
      for (int nj = 0; nj < 4; ++nj) bv[nj] = ldfrag(Bbuf, wc * 64 + 16 * nj + c, 4 + g);
#pragma unroll
      for (int mi = 0; mi < 4; ++mi) av[mi] = ldfrag(Abuf, wr * 64 + 16 * mi + c, 4 + g);
      __builtin_amdgcn_s_setprio(1);
#pragma unroll
      for (int mi = 0; mi < 4; ++mi)
#pragma unroll
        for (int nj = 0; nj < 4; ++nj)
          acc[mi][nj] = __builtin_amdgcn_mfma_f32_16x16x32_bf16(av[mi], bv[nj], acc[mi][nj], 0, 0, 0);
      __builtin_amdgcn_s_setprio(0);
    }
    if (tt + 1 < KT) {
      // boundary: tile t+1 fully landed; t+2's 6 loads may stay in flight
      if (pf)
        VMW(6);
      else
        VMW(0);
      __builtin_amdgcn_s_barrier();
    }
  }

  // ---- epilogue ----
#pragma unroll
  for (int nj = 0; nj < 4; ++nj) {
    int col = (int)n0 + wc * 64 + 16 * nj + c;
    float bvv = bias[col];
#pragma unroll
    for (int mi = 0; mi < 4; ++mi) {
      size_t rbase = m0 + wr * 64 + 16 * mi + 4 * g;
#pragma unroll
      for (int r = 0; r < 4; ++r) {
        float f = acc[mi][nj][r] + bvv;
        if (mode == 1) f = 0.5f * f * (1.0f + erff(f * 0.70710678f));
        size_t oidx = (rbase + r) * (size_t)ldc + col;
        if (mode == 2)
          ((float*)Cout)[oidx] = f;
        else
          ((u16*)Cout)[oidx] = f2bf(f);
      }
    }
  }
}

// ---------------- sliding-window causal attention ----------------
// 1 wave per 32-query tile, no barriers. grid = B*NH*(S/32) = 4096, block = 64.
// Q pre-scaled by 0.125. K frags direct global; V frags direct from vT.
// XCD-swizzled so neighboring q-tiles (overlapping K/V windows) share an L2.
__global__ __launch_bounds__(64, 4) void attn_kernel(const u16* __restrict__ qkv,
                                                     const u16* __restrict__ vT,
                                                     u16* __restrict__ comb) {
  int bid = blockIdx.x;
  int swz = ((bid & 7) << 9) + (bid >> 3);  // 4096/8 = 512 per XCD
  int qt = swz & 127, h = (swz >> 7) & 15, b = swz >> 11;
  int l = threadIdx.x, c = l & 15, g = l >> 4;
  int q0 = qt * 32;
  const u16* qb = qkv + (size_t)b * 4096 * 3072 + h * 64;
  const u16* kb = qb + 1024;
  const u16* vt = vT + (size_t)(b * 16 + h) * 64 * 4096;
  __shared__ u16 Pl[32 * 72];

  short8 qf[2][2];
#pragma unroll
  for (int mi = 0; mi < 2; ++mi)
#pragma unroll
    for (int kk = 0; kk < 2; ++kk)
      qf[mi][kk] = *reinterpret_cast<const short8*>(
          qb + (size_t)(q0 + 16 * mi + c) * 3072 + 32 * kk + 8 * g);

  f32x4 zero4 = {0.f, 0.f, 0.f, 0.f};
  f32x4 o[2][4];
  float mr[2][4], lr[2][4];
#pragma unroll
  for (int a = 0; a < 2; ++a)
#pragma unroll
    for (int d2 = 0; d2 < 4; ++d2) {
      o[a][d2] = zero4;
      mr[a][d2] = -1e30f;
      lr[a][d2] = 0.f;
    }

  int t_lo = (q0 >= 480) ? ((q0 - 480) >> 6) : 0;
  int t_hi = (q0 + 31) >> 6;
  for (int tt = t_lo; tt <= t_hi; ++tt) {
    int kt0 = tt * 64;
    f32x4 s[2][4];
#pragma unroll
    for (int a = 0; a < 2; ++a)
#pragma unroll
      for (int d2 = 0; d2 < 4; ++d2) s[a][d2] = zero4;

#pragma unroll
    for (int kk = 0; kk < 2; ++kk) {
      short8 kf[4];
#pragma unroll
      for (int nj = 0; nj < 4; ++nj)
        kf[nj] = *reinterpret_cast<const short8*>(
            kb + (size_t)(kt0 + 16 * nj + c) * 3072 + 32 * kk + 8 * g);
#pragma unroll
      for (int mi = 0; mi < 2; ++mi)
#pragma unroll
        for (int nj = 0; nj < 4; ++nj)
          s[mi][nj] = __builtin_amdgcn_mfma_f32_16x16x32_bf16(qf[mi][kk], kf[nj], s[mi][nj], 0, 0, 0);
    }

    // mask only on the boundary tiles (wave-uniform branch)
    bool mc = (tt == t_hi), mw = (tt == t_lo);
    if (mc | mw) {
#pragma unroll
      for (int mi = 0; mi < 2; ++mi)
#pragma unroll
        for (int nj = 0; nj < 4; ++nj)
#pragma unroll
          for (int r = 0; r < 4; ++r) {
            int qg = q0 + 16 * mi + 4 * g + r;
            int kg = kt0 + 16 * nj + c;
            if ((mc && kg > qg) || (mw && qg - kg >= 512)) s[mi][nj][r] = -1e30f;
          }
    }

#pragma unroll
    for (int mi = 0; mi < 2; ++mi)
#pragma unroll
      for (int r = 0; r < 4; ++r) {
        float tm = fmaxf(fmaxf(s[mi][0][r], s[mi][1][r]), fmaxf(s[mi][2][r], s[mi][3][r]));
        tm = redmax16(tm);
        float mn = fmaxf(mr[mi][r], tm);
        float a = __expf(mr[mi][r] - mn);
        mr[mi][r] = mn;
        float rs = 0.f;
        u16* pp = &Pl[(16 * mi + 4 * g + r) * 72 + c];
#pragma unroll
        for (int nj = 0; nj < 4; ++nj) {
          float p = __expf(s[mi][nj][r] - mn);
          rs += p;
          pp[16 * nj] = f2bf(p);  // natural k order, imm-offset ds_write_b16
        }
        rs = redsum16(rs);
        lr[mi][r] = lr[mi][r] * a + rs;
#pragma unroll
        for (int dj = 0; dj < 4; ++dj) o[mi][dj][r] *= a;
      }

    // PV: A-frag from Pl (natural order), B-frag = k-contiguous rows of vT
#pragma unroll
    for (int kk = 0; kk < 2; ++kk) {
      short8 pa[2];
#pragma unroll
      for (int mi = 0; mi < 2; ++mi)
        pa[mi] = *reinterpret_cast<const short8*>(&Pl[(16 * mi + c) * 72 + 32 * kk + 8 * g]);
      short8 bv[4];
#pragma unroll
      for (int dj = 0; dj < 4; ++dj)
        bv[dj] = *reinterpret_cast<const short8*>(
            vt + (size_t)(16 * dj + c) * 4096 + kt0 + 32 * kk + 8 * g);
#pragma unroll
      for (int mi = 0; mi < 2; ++mi)
#pragma unroll
        for (int dj = 0; dj < 4; ++dj)
          o[mi][dj] = __builtin_amdgcn_mfma_f32_16x16x32_bf16(pa[mi], bv[dj], o[mi][dj], 0, 0, 0);
    }
  }

  u16* ob = comb + (size_t)(b * 4096 + q0) * 5120 + h * 64;
#pragma unroll
  for (int mi = 0; mi < 2; ++mi)
#pragma unroll
    for (int r = 0; r < 4; ++r) {
      float inv = __builtin_amdgcn_rcpf(lr[mi][r]);
#pragma unroll
      for (int dj = 0; dj < 4; ++dj)
        ob[(size_t)(16 * mi + 4 * g + r) * 5120 + 16 * dj + c] = f2bf(o[mi][dj][r] * inv);
    }
}

// ---------------- launch ----------------
extern "C" void kernel_launch(void* const* d_in, const int* in_sizes, int n_in,
                              void* d_out, int out_size, void* d_ws, size_t ws_size,
                              hipStream_t stream) {
  const float* x = (const float*)d_in[0];
  const float* sinp = (const float*)d_in[1];
  const float* cosp = (const float*)d_in[2];
  const float* norm_w = (const float*)d_in[3];
  const float* w_qkv = (const float*)d_in[4];
  const float* b_qkv = (const float*)d_in[5];
  const float* w_in = (const float*)d_in[6];
  const float* b_in = (const float*)d_in[7];
  const float* w_out = (const float*)d_in[8];
  const float* b_out = (const float*)d_in[9];
  float* out = (float*)d_out;

  char* ws = (char*)d_ws;
  u16* xn = (u16*)(ws);                        // 8192*1024*2      = 16,777,216
  u16* vT = (u16*)(ws);                        // aliases xn (xn dead after FF gemm)
  u16* qkv = (u16*)(ws + 16777216);            // 8192*3072*2      = 50,331,648
  u16* comb = (u16*)(ws + 67108864);           // 8192*5120*2      = 83,886,080
  u16* wqkvT = (u16*)(ws + 150994944);         // 3072*1024*2      = 6,291,456
  u16* winT = (u16*)(ws + 157286400);          // 4096*1024*2      = 8,388,608
  u16* woutT = (u16*)(ws + 165675008);         // 1024*5120*2      = 10,485,760

  transpose_f32_bf16<<<dim3(3072 / 32, 1024 / 32), 256, 0, stream>>>(w_qkv, wqkvT, 1024, 3072);
  transpose_f32_bf16<<<dim3(4096 / 32, 1024 / 32), 256, 0, stream>>>(w_in, winT, 1024, 4096);
  transpose_f32_bf16<<<dim3(1024 / 32, 5120 / 32), 256, 0, stream>>>(w_out, woutT, 5120, 1024);

  rmsnorm_kernel<<<8192, 256, 0, stream>>>(x, norm_w, xn);

  // qkv = xn @ w_qkv + b_qkv   (bf16 out)
  gemm256<<<dim3(3072 / 128, 8192 / 256), 512, 0, stream>>>(xn, wqkvT, b_qkv, qkv, 1024, 3072, 0);

  rope_kernel<<<8192, 256, 0, stream>>>(qkv, sinp, cosp);

  // ff = gelu(xn @ w_in + b_in) -> comb cols [1024, 5120)  (bf16 out; last use of xn)
  gemm256<<<dim3(4096 / 128, 8192 / 256), 512, 0, stream>>>(xn, winT, b_in, comb + 1024, 1024, 5120, 1);

  // vT[b,h][d][s] = V  (into xn's region; xn dead after FF gemm)
  transpose_v<<<dim3(128, 2, 32), 256, 0, stream>>>(qkv, vT);

  attn_kernel<<<4096, 64, 0, stream>>>(qkv, vT, comb);

  // out = comb @ w_out + b_out  (f32 out)
  gemm256<<<dim3(1024 / 128, 8192 / 256), 512, 0, stream>>>(comb, woutT, b_out, out, 5120, 1024, 2);
}